// Round 3
// baseline (244.586 us; speedup 1.0000x reference)
//
#include <hip/hip_runtime.h>
#include <hip/hip_bf16.h>
#include <stdint.h>

#define N_ROWS 8192
#define DIM    1024
#define BM 128
#define BN 128
#define BKF 128          // fp8 bytes of K per tile (= one MFMA K)
#define NT (DIM / BKF)   // 8 K-tiles

typedef float   f32x4  __attribute__((ext_vector_type(4)));
typedef int     i32x4  __attribute__((ext_vector_type(4)));
typedef int     i32x8  __attribute__((ext_vector_type(8)));

// ---------------------------------------------------------------------------
// Kernel 1: fused L2-normalize (fp32 -> fp8 e4m3) + exact fp32 per-row
// diagonal + S zero-init (folds the memset dispatch).  UNCHANGED.
// ---------------------------------------------------------------------------
__global__ __launch_bounds__(256) void nrm_kernel(
    const float* __restrict__ img, const float* __restrict__ txt,
    uint8_t* __restrict__ img_f8, uint8_t* __restrict__ txt_f8,
    float* __restrict__ diag, float* __restrict__ S)
{
    const int row  = blockIdx.x;
    const int t    = threadIdx.x;
    const int lane = t & 63;
    const int w    = t >> 6;

    const float4 a = ((const float4*)(img + (size_t)row * DIM))[t];
    const float4 b = ((const float4*)(txt + (size_t)row * DIM))[t];

    float sa = a.x * a.x + a.y * a.y + a.z * a.z + a.w * a.w;
    float sb = b.x * b.x + b.y * b.y + b.z * b.z + b.w * b.w;
#pragma unroll
    for (int d = 1; d < 64; d <<= 1) {
        sa += __shfl_xor(sa, d, 64);
        sb += __shfl_xor(sb, d, 64);
    }
    __shared__ float red[3][4];
    if (lane == 0) { red[0][w] = sa; red[1][w] = sb; }
    __syncthreads();
    sa = red[0][0] + red[0][1] + red[0][2] + red[0][3];
    sb = red[1][0] + red[1][1] + red[1][2] + red[1][3];

    const float ia = 1.0f / fmaxf(sqrtf(sa), 1e-12f);
    const float ib = 1.0f / fmaxf(sqrtf(sb), 1e-12f);

    int ra = 0, rb = 0;
    ra = __builtin_amdgcn_cvt_pk_fp8_f32(a.x * ia, a.y * ia, ra, false);
    ra = __builtin_amdgcn_cvt_pk_fp8_f32(a.z * ia, a.w * ia, ra, true);
    rb = __builtin_amdgcn_cvt_pk_fp8_f32(b.x * ib, b.y * ib, rb, false);
    rb = __builtin_amdgcn_cvt_pk_fp8_f32(b.z * ib, b.w * ib, rb, true);
    ((int*)(img_f8 + (size_t)row * DIM))[t] = ra;
    ((int*)(txt_f8 + (size_t)row * DIM))[t] = rb;

    float dp = (a.x * b.x + a.y * b.y + a.z * b.z + a.w * b.w) * ia * ib;
#pragma unroll
    for (int d = 1; d < 64; d <<= 1) dp += __shfl_xor(dp, d, 64);
    if (lane == 0) red[2][w] = dp;
    __syncthreads();
    if (t == 0) {
        diag[row] = red[2][0] + red[2][1] + red[2][2] + red[2][3];
        S[row] = 0.0f;
    }
}

// ---------------------------------------------------------------------------
// Kernel 2: 128x128-tile MX-fp8 MFMA GEMM (C = A . B^T), T3-minimum pipeline.
//   4 waves (2x2), wave tile 64x64, acc[4][4] f32x4 (64 regs) — the verified
//   R0 fragment/epilogue code.  NEW: LDS double-buffer 2 x 32 KiB = 64 KiB
//   (2 blocks/CU for cross-block latency fill) and the K-loop restructured to
//   { STAGE(next tile)  ->  ds_read(cur) + 16 MFMA  ->  vmcnt(0); barrier }
//   so the L2->LDS transfer overlaps the current tile's compute instead of
//   draining cold before it (R0/R2's shared exposed stall: both pipes <40%
//   busy while dur was 3000 cy/K-step).  No sched_barrier / lgkmcnt asm /
//   setprio: compiler sees the C++ LDS loads and schedules fine-grained.
//   XOR chunk swizzle kept (chunk c of row r at c^(r&7), via permuted global
//   source; read side XORs the same key) — verified 0-extra-conflict in R0.
//   Fused epilogue: rowsum of exp(sim - 1) -> atomicAdd into S[row].
// ---------------------------------------------------------------------------
__global__ __launch_bounds__(256) void sim_lse_kernel(
    const uint8_t* __restrict__ A, const uint8_t* __restrict__ B,
    float* __restrict__ S)
{
    // buffer k at k*32768: A tile 16 KiB then B tile 16 KiB
    __shared__ __align__(16) uint8_t smem[2 * 2 * BM * BKF];   // 64 KiB

    const int t     = threadIdx.x;       // 0..255
    const int lane  = t & 63;
    const int w     = t >> 6;            // wave 0..3
    const int waveM = w >> 1;            // 2x2 wave grid, 64x64 each
    const int waveN = w & 1;
    const int lr    = lane & 15;         // row-in-16-tile
    const int q     = lane >> 4;         // k-quarter (f8f6f4 frag layout)
    const int swz   = lr & 7;            // read-side XOR swizzle key

    const int rowA0 = blockIdx.y * BM;
    const int rowB0 = blockIdx.x * BN;
    const uint8_t* Ablk = A + (size_t)rowA0 * DIM;
    const uint8_t* Bblk = B + (size_t)rowB0 * DIM;

    const uint32_t lo_off = (uint32_t)(((2 * q) ^ swz) * 16);

    f32x4 acc[4][4] = {};

    // stage one K-tile (A 16K + B 16K) into buffer at ldsbase; 8 loads/thread
    auto stage = [&](int k0, uint32_t ldsbase) {
#pragma unroll
        for (int is = 0; is < 4; ++is) {
            const int c   = is * 256 + t;        // 16B chunk id, 0..1023
            const int row = c >> 3;              // 0..127 (128 B rows)
            const int col = (c & 7) ^ (row & 7); // pre-swizzled source chunk
            __builtin_amdgcn_global_load_lds(
                (const __attribute__((address_space(1))) void*)
                    (Ablk + (size_t)row * DIM + k0 + col * 16),
                (__attribute__((address_space(3))) void*)
                    &smem[ldsbase + (uint32_t)c * 16],
                16, 0, 0);
            __builtin_amdgcn_global_load_lds(
                (const __attribute__((address_space(1))) void*)
                    (Bblk + (size_t)row * DIM + k0 + col * 16),
                (__attribute__((address_space(3))) void*)
                    &smem[ldsbase + 16384u + (uint32_t)c * 16],
                16, 0, 0);
        }
    };

    // ---- prologue: stage K-tile 0 into buffer 0, full drain once ----------
    stage(0, 0u);
    asm volatile("s_waitcnt vmcnt(0)" ::: "memory");
    __builtin_amdgcn_s_barrier();

    // ---- main loop: prefetch next || compute current; 1 drain+barrier -----
#pragma unroll 1
    for (int kt = 0; kt < NT; ++kt) {
        const uint32_t cur = (uint32_t)((kt & 1) << 15);   // 0 / 32768
        const uint32_t nxt = cur ^ 32768u;

        if (kt < NT - 1) stage((kt + 1) * BKF, nxt);   // issue, don't wait

        // Fragments (verified R0 code): lane holds k = q*32..q*32+31 of row
        // (waveX*64 + i*16 + lr) = source chunks {2q,2q+1}, each at (c^swz).
        i32x8 af[4], bfr[4];
#pragma unroll
        for (int mi = 0; mi < 4; ++mi) {
            const uint8_t* base = &smem[cur + (uint32_t)((waveM * 64 + mi * 16 + lr) * BKF)];
            i32x4 lo = *(const i32x4*)&base[lo_off];
            i32x4 hi = *(const i32x4*)&base[lo_off ^ 16u];
            af[mi] = (i32x8){lo.x, lo.y, lo.z, lo.w, hi.x, hi.y, hi.z, hi.w};
        }
#pragma unroll
        for (int ni = 0; ni < 4; ++ni) {
            const uint8_t* base = &smem[cur + 16384u + (uint32_t)((waveN * 64 + ni * 16 + lr) * BKF)];
            i32x4 lo = *(const i32x4*)&base[lo_off];
            i32x4 hi = *(const i32x4*)&base[lo_off ^ 16u];
            bfr[ni] = (i32x8){lo.x, lo.y, lo.z, lo.w, hi.x, hi.y, hi.z, hi.w};
        }
#pragma unroll
        for (int mi = 0; mi < 4; ++mi)
#pragma unroll
            for (int ni = 0; ni < 4; ++ni)
                acc[mi][ni] = __builtin_amdgcn_mfma_scale_f32_16x16x128_f8f6f4(
                    af[mi], bfr[ni], acc[mi][ni],
                    0 /*fmtA=fp8*/, 0 /*fmtB=fp8*/,
                    0, 127 /*scaleA=1.0*/, 0, 127 /*scaleB=1.0*/);

        // next tile's loads had the whole compute phase to land: cheap drain.
        asm volatile("s_waitcnt vmcnt(0)" ::: "memory");
        __builtin_amdgcn_s_barrier();
    }

    // ---- epilogue (verified R0 code): exp(s-1), rowsum, atomic into S -----
    // C/D layout (shape-determined): col = lane&15, row = (lane>>4)*4 + reg
    const float L2E = 1.44269504088896f;
    const int rowbase = rowA0 + waveM * 64;
#pragma unroll
    for (int mi = 0; mi < 4; ++mi) {
        float p0 = 0.f, p1 = 0.f, p2 = 0.f, p3 = 0.f;
#pragma unroll
        for (int ni = 0; ni < 4; ++ni) {
            p0 += exp2f(acc[mi][ni].x * L2E - L2E);
            p1 += exp2f(acc[mi][ni].y * L2E - L2E);
            p2 += exp2f(acc[mi][ni].z * L2E - L2E);
            p3 += exp2f(acc[mi][ni].w * L2E - L2E);
        }
#pragma unroll
        for (int d = 1; d < 16; d <<= 1) {
            p0 += __shfl_xor(p0, d, 64);
            p1 += __shfl_xor(p1, d, 64);
            p2 += __shfl_xor(p2, d, 64);
            p3 += __shfl_xor(p3, d, 64);
        }
        if ((lane & 15) == 0) {
            float* dst = &S[rowbase + mi * 16 + (lane >> 4) * 4];
            atomicAdd(dst + 0, p0);
            atomicAdd(dst + 1, p1);
            atomicAdd(dst + 2, p2);
            atomicAdd(dst + 3, p3);
        }
    }
}

// ---------------------------------------------------------------------------
// Kernel 3: out = mean(log(S_i) - diag_i)   UNCHANGED
// ---------------------------------------------------------------------------
__global__ __launch_bounds__(1024) void fin_kernel(
    const float* __restrict__ S, const float* __restrict__ diag,
    float* __restrict__ out)
{
    const int t = threadIdx.x;
    float s = 0.f;
    for (int i = t; i < N_ROWS; i += 1024) s += logf(S[i]) - diag[i];
#pragma unroll
    for (int d = 1; d < 64; d <<= 1) s += __shfl_xor(s, d, 64);
    __shared__ float red[16];
    if ((t & 63) == 0) red[t >> 6] = s;
    __syncthreads();
    if (t == 0) {
        float tot = 0.f;
#pragma unroll
        for (int i = 0; i < 16; ++i) tot += red[i];
        out[0] = tot * (1.0f / N_ROWS);
    }
}

// ---------------------------------------------------------------------------
extern "C" void kernel_launch(void* const* d_in, const int* in_sizes, int n_in,
                              void* d_out, int out_size, void* d_ws, size_t ws_size,
                              hipStream_t stream)
{
    const float* img = (const float*)d_in[0];
    const float* txt = (const float*)d_in[1];
    float* out = (float*)d_out;

    char* ws = (char*)d_ws;
    uint8_t* img_f8 = (uint8_t*)ws;                                  // 8 MiB
    uint8_t* txt_f8 = (uint8_t*)(ws + (size_t)N_ROWS * DIM);         // 8 MiB
    float*   S      = (float*)(ws + (size_t)N_ROWS * DIM * 2);       // 32 KiB
    float*   diag   = S + N_ROWS;                                    // 32 KiB

    nrm_kernel<<<N_ROWS, 256, 0, stream>>>(img, txt, img_f8, txt_f8, diag, S);
    dim3 grid(N_ROWS / BN, N_ROWS / BM);
    sim_lse_kernel<<<grid, 256, 0, stream>>>(img_f8, txt_f8, S);
    fin_kernel<<<1, 1024, 0, stream>>>(S, diag, out);
}

// Round 4
// 240.355 us; speedup vs baseline: 1.0176x; 1.0176x over previous
//
#include <hip/hip_runtime.h>
#include <hip/hip_bf16.h>
#include <stdint.h>

#define N_ROWS 8192
#define DIM    1024
#define BM 128
#define BN 128
#define BKF 128          // fp8 bytes of K per tile (= one MFMA K)
#define NT (DIM / BKF)   // 8 K-tiles

typedef float   f32x4  __attribute__((ext_vector_type(4)));
typedef int     i32x4  __attribute__((ext_vector_type(4)));
typedef int     i32x8  __attribute__((ext_vector_type(8)));

// 16-lane (DPP row) sum via v_add_f32 + row_ror — NO LDS TRAFFIC.
// R0/R2/R3 all showed SQ_LDS_BANK_CONFLICT == 2^23 == (#epilogue __shfl_xor
// bpermutes) * 8: the epilogue shuffle-reduce was 100% of the bank conflicts
// (~65k cy/CU of LDS time at each block's tail).  row_ror:{8,4,2,1} rotates
// within the 16-lane DPP row: after 4 adds every lane holds the row sum.
__device__ __forceinline__ float row_sum16(float x) {
    x += __int_as_float(__builtin_amdgcn_update_dpp(
            0, __float_as_int(x), 0x128 /*row_ror:8*/, 0xf, 0xf, true));
    x += __int_as_float(__builtin_amdgcn_update_dpp(
            0, __float_as_int(x), 0x124 /*row_ror:4*/, 0xf, 0xf, true));
    x += __int_as_float(__builtin_amdgcn_update_dpp(
            0, __float_as_int(x), 0x122 /*row_ror:2*/, 0xf, 0xf, true));
    x += __int_as_float(__builtin_amdgcn_update_dpp(
            0, __float_as_int(x), 0x121 /*row_ror:1*/, 0xf, 0xf, true));
    return x;
}

// ---------------------------------------------------------------------------
// Kernel 1: fused L2-normalize (fp32 -> fp8 e4m3) + exact fp32 per-row
// diagonal + S zero-init (folds the memset dispatch).  UNCHANGED.
// ---------------------------------------------------------------------------
__global__ __launch_bounds__(256) void nrm_kernel(
    const float* __restrict__ img, const float* __restrict__ txt,
    uint8_t* __restrict__ img_f8, uint8_t* __restrict__ txt_f8,
    float* __restrict__ diag, float* __restrict__ S)
{
    const int row  = blockIdx.x;
    const int t    = threadIdx.x;
    const int lane = t & 63;
    const int w    = t >> 6;

    const float4 a = ((const float4*)(img + (size_t)row * DIM))[t];
    const float4 b = ((const float4*)(txt + (size_t)row * DIM))[t];

    float sa = a.x * a.x + a.y * a.y + a.z * a.z + a.w * a.w;
    float sb = b.x * b.x + b.y * b.y + b.z * b.z + b.w * b.w;
#pragma unroll
    for (int d = 1; d < 64; d <<= 1) {
        sa += __shfl_xor(sa, d, 64);
        sb += __shfl_xor(sb, d, 64);
    }
    __shared__ float red[3][4];
    if (lane == 0) { red[0][w] = sa; red[1][w] = sb; }
    __syncthreads();
    sa = red[0][0] + red[0][1] + red[0][2] + red[0][3];
    sb = red[1][0] + red[1][1] + red[1][2] + red[1][3];

    const float ia = 1.0f / fmaxf(sqrtf(sa), 1e-12f);
    const float ib = 1.0f / fmaxf(sqrtf(sb), 1e-12f);

    int ra = 0, rb = 0;
    ra = __builtin_amdgcn_cvt_pk_fp8_f32(a.x * ia, a.y * ia, ra, false);
    ra = __builtin_amdgcn_cvt_pk_fp8_f32(a.z * ia, a.w * ia, ra, true);
    rb = __builtin_amdgcn_cvt_pk_fp8_f32(b.x * ib, b.y * ib, rb, false);
    rb = __builtin_amdgcn_cvt_pk_fp8_f32(b.z * ib, b.w * ib, rb, true);
    ((int*)(img_f8 + (size_t)row * DIM))[t] = ra;
    ((int*)(txt_f8 + (size_t)row * DIM))[t] = rb;

    float dp = (a.x * b.x + a.y * b.y + a.z * b.z + a.w * b.w) * ia * ib;
#pragma unroll
    for (int d = 1; d < 64; d <<= 1) dp += __shfl_xor(dp, d, 64);
    if (lane == 0) red[2][w] = dp;
    __syncthreads();
    if (t == 0) {
        diag[row] = red[2][0] + red[2][1] + red[2][2] + red[2][3];
        S[row] = 0.0f;
    }
}

// ---------------------------------------------------------------------------
// Kernel 2: 128x128-tile MX-fp8 MFMA GEMM (C = A . B^T), T3-minimum pipeline
// (R3 structure, unchanged): LDS double-buffer 2 x 32 KiB; per K-tile
// { STAGE(next) -> ds_read(cur) + 16 MFMA -> vmcnt(0); barrier }.
// CHANGED vs R3: epilogue reduction is now DPP row_ror (row_sum16) instead of
// __shfl_xor/ds_bpermute — removes ALL measured LDS bank conflicts (2^23 ==
// 1.05M bpermutes x 8 cy, bit-exact across R0/R2/R3) and the per-block
// serial LDS-crossbar tail.
// XOR chunk swizzle kept (chunk c of row r at c^(r&7), via permuted global
// source; read side XORs the same key) — K-loop itself is conflict-free.
// ---------------------------------------------------------------------------
__global__ __launch_bounds__(256) void sim_lse_kernel(
    const uint8_t* __restrict__ A, const uint8_t* __restrict__ B,
    float* __restrict__ S)
{
    // buffer k at k*32768: A tile 16 KiB then B tile 16 KiB
    __shared__ __align__(16) uint8_t smem[2 * 2 * BM * BKF];   // 64 KiB

    const int t     = threadIdx.x;       // 0..255
    const int lane  = t & 63;
    const int w     = t >> 6;            // wave 0..3
    const int waveM = w >> 1;            // 2x2 wave grid, 64x64 each
    const int waveN = w & 1;
    const int lr    = lane & 15;         // row-in-16-tile
    const int q     = lane >> 4;         // k-quarter (f8f6f4 frag layout)
    const int swz   = lr & 7;            // read-side XOR swizzle key

    const int rowA0 = blockIdx.y * BM;
    const int rowB0 = blockIdx.x * BN;
    const uint8_t* Ablk = A + (size_t)rowA0 * DIM;
    const uint8_t* Bblk = B + (size_t)rowB0 * DIM;

    const uint32_t lo_off = (uint32_t)(((2 * q) ^ swz) * 16);

    f32x4 acc[4][4] = {};

    // stage one K-tile (A 16K + B 16K) into buffer at ldsbase; 8 loads/thread
    auto stage = [&](int k0, uint32_t ldsbase) {
#pragma unroll
        for (int is = 0; is < 4; ++is) {
            const int c   = is * 256 + t;        // 16B chunk id, 0..1023
            const int row = c >> 3;              // 0..127 (128 B rows)
            const int col = (c & 7) ^ (row & 7); // pre-swizzled source chunk
            __builtin_amdgcn_global_load_lds(
                (const __attribute__((address_space(1))) void*)
                    (Ablk + (size_t)row * DIM + k0 + col * 16),
                (__attribute__((address_space(3))) void*)
                    &smem[ldsbase + (uint32_t)c * 16],
                16, 0, 0);
            __builtin_amdgcn_global_load_lds(
                (const __attribute__((address_space(1))) void*)
                    (Bblk + (size_t)row * DIM + k0 + col * 16),
                (__attribute__((address_space(3))) void*)
                    &smem[ldsbase + 16384u + (uint32_t)c * 16],
                16, 0, 0);
        }
    };

    // ---- prologue: stage K-tile 0 into buffer 0, full drain once ----------
    stage(0, 0u);
    asm volatile("s_waitcnt vmcnt(0)" ::: "memory");
    __builtin_amdgcn_s_barrier();

    // ---- main loop: prefetch next || compute current; 1 drain+barrier -----
#pragma unroll 1
    for (int kt = 0; kt < NT; ++kt) {
        const uint32_t cur = (uint32_t)((kt & 1) << 15);   // 0 / 32768
        const uint32_t nxt = cur ^ 32768u;

        if (kt < NT - 1) stage((kt + 1) * BKF, nxt);   // issue, don't wait

        // Fragments: lane holds k = q*32..q*32+31 of row (waveX*64 + i*16+lr)
        // = source chunks {2q,2q+1}, each at LDS chunk (c^swz).
        i32x8 af[4], bfr[4];
#pragma unroll
        for (int mi = 0; mi < 4; ++mi) {
            const uint8_t* base = &smem[cur + (uint32_t)((waveM * 64 + mi * 16 + lr) * BKF)];
            i32x4 lo = *(const i32x4*)&base[lo_off];
            i32x4 hi = *(const i32x4*)&base[lo_off ^ 16u];
            af[mi] = (i32x8){lo.x, lo.y, lo.z, lo.w, hi.x, hi.y, hi.z, hi.w};
        }
#pragma unroll
        for (int ni = 0; ni < 4; ++ni) {
            const uint8_t* base = &smem[cur + 16384u + (uint32_t)((waveN * 64 + ni * 16 + lr) * BKF)];
            i32x4 lo = *(const i32x4*)&base[lo_off];
            i32x4 hi = *(const i32x4*)&base[lo_off ^ 16u];
            bfr[ni] = (i32x8){lo.x, lo.y, lo.z, lo.w, hi.x, hi.y, hi.z, hi.w};
        }
#pragma unroll
        for (int mi = 0; mi < 4; ++mi)
#pragma unroll
            for (int ni = 0; ni < 4; ++ni)
                acc[mi][ni] = __builtin_amdgcn_mfma_scale_f32_16x16x128_f8f6f4(
                    af[mi], bfr[ni], acc[mi][ni],
                    0 /*fmtA=fp8*/, 0 /*fmtB=fp8*/,
                    0, 127 /*scaleA=1.0*/, 0, 127 /*scaleB=1.0*/);

        // next tile's loads had the whole compute phase to land: cheap drain.
        asm volatile("s_waitcnt vmcnt(0)" ::: "memory");
        __builtin_amdgcn_s_barrier();
    }

    // ---- epilogue: exp(s-1), DPP row-sum over 16 lanes, atomic into S -----
    // C/D layout (shape-determined): col = lane&15, row = (lane>>4)*4 + reg
    const float L2E = 1.44269504088896f;
    const int rowbase = rowA0 + waveM * 64;
#pragma unroll
    for (int mi = 0; mi < 4; ++mi) {
        float p0 = 0.f, p1 = 0.f, p2 = 0.f, p3 = 0.f;
#pragma unroll
        for (int ni = 0; ni < 4; ++ni) {
            p0 += exp2f(acc[mi][ni].x * L2E - L2E);
            p1 += exp2f(acc[mi][ni].y * L2E - L2E);
            p2 += exp2f(acc[mi][ni].z * L2E - L2E);
            p3 += exp2f(acc[mi][ni].w * L2E - L2E);
        }
        p0 = row_sum16(p0);   // VALU-only (DPP), zero LDS traffic
        p1 = row_sum16(p1);
        p2 = row_sum16(p2);
        p3 = row_sum16(p3);
        if ((lane & 15) == 0) {
            float* dst = &S[rowbase + mi * 16 + (lane >> 4) * 4];
            atomicAdd(dst + 0, p0);
            atomicAdd(dst + 1, p1);
            atomicAdd(dst + 2, p2);
            atomicAdd(dst + 3, p3);
        }
    }
}

// ---------------------------------------------------------------------------
// Kernel 3: out = mean(log(S_i) - diag_i)   UNCHANGED
// ---------------------------------------------------------------------------
__global__ __launch_bounds__(1024) void fin_kernel(
    const float* __restrict__ S, const float* __restrict__ diag,
    float* __restrict__ out)
{
    const int t = threadIdx.x;
    float s = 0.f;
    for (int i = t; i < N_ROWS; i += 1024) s += logf(S[i]) - diag[i];
#pragma unroll
    for (int d = 1; d < 64; d <<= 1) s += __shfl_xor(s, d, 64);
    __shared__ float red[16];
    if ((t & 63) == 0) red[t >> 6] = s;
    __syncthreads();
    if (t == 0) {
        float tot = 0.f;
#pragma unroll
        for (int i = 0; i < 16; ++i) tot += red[i];
        out[0] = tot * (1.0f / N_ROWS);
    }
}

// ---------------------------------------------------------------------------
extern "C" void kernel_launch(void* const* d_in, const int* in_sizes, int n_in,
                              void* d_out, int out_size, void* d_ws, size_t ws_size,
                              hipStream_t stream)
{
    const float* img = (const float*)d_in[0];
    const float* txt = (const float*)d_in[1];
    float* out = (float*)d_out;

    char* ws = (char*)d_ws;
    uint8_t* img_f8 = (uint8_t*)ws;                                  // 8 MiB
    uint8_t* txt_f8 = (uint8_t*)(ws + (size_t)N_ROWS * DIM);         // 8 MiB
    float*   S      = (float*)(ws + (size_t)N_ROWS * DIM * 2);       // 32 KiB
    float*   diag   = S + N_ROWS;                                    // 32 KiB

    nrm_kernel<<<N_ROWS, 256, 0, stream>>>(img, txt, img_f8, txt_f8, diag, S);
    dim3 grid(N_ROWS / BN, N_ROWS / BM);
    sim_lse_kernel<<<grid, 256, 0, stream>>>(img_f8, txt_f8, S);
    fin_kernel<<<1, 1024, 0, stream>>>(S, diag, out);
}

// Round 5
// 233.821 us; speedup vs baseline: 1.0460x; 1.0279x over previous
//
#include <hip/hip_runtime.h>
#include <hip/hip_bf16.h>
#include <stdint.h>

#define N_ROWS 8192
#define DIM    1024
#define BM 256           // block rows (A panel)
#define BN 128           // block cols (B panel)
#define BKF 128          // fp8 bytes of K per tile (= one MFMA K)
#define NT (DIM / BKF)   // 8 K-tiles
#define BUF_SZ 49152u    // per K-tile buffer: A 32 KiB + B 16 KiB

typedef float   f32x4  __attribute__((ext_vector_type(4)));
typedef int     i32x4  __attribute__((ext_vector_type(4)));
typedef int     i32x8  __attribute__((ext_vector_type(8)));

// 16-lane (DPP row) sum via v_add_f32 + row_ror — no LDS traffic (R4, kept).
__device__ __forceinline__ float row_sum16(float x) {
    x += __int_as_float(__builtin_amdgcn_update_dpp(
            0, __float_as_int(x), 0x128 /*row_ror:8*/, 0xf, 0xf, true));
    x += __int_as_float(__builtin_amdgcn_update_dpp(
            0, __float_as_int(x), 0x124 /*row_ror:4*/, 0xf, 0xf, true));
    x += __int_as_float(__builtin_amdgcn_update_dpp(
            0, __float_as_int(x), 0x122 /*row_ror:2*/, 0xf, 0xf, true));
    x += __int_as_float(__builtin_amdgcn_update_dpp(
            0, __float_as_int(x), 0x121 /*row_ror:1*/, 0xf, 0xf, true));
    return x;
}

// ---------------------------------------------------------------------------
// Kernel 1: fused L2-normalize (fp32 -> fp8 e4m3) + exact fp32 per-row
// diagonal + S zero-init.  UNCHANGED.
// ---------------------------------------------------------------------------
__global__ __launch_bounds__(256) void nrm_kernel(
    const float* __restrict__ img, const float* __restrict__ txt,
    uint8_t* __restrict__ img_f8, uint8_t* __restrict__ txt_f8,
    float* __restrict__ diag, float* __restrict__ S)
{
    const int row  = blockIdx.x;
    const int t    = threadIdx.x;
    const int lane = t & 63;
    const int w    = t >> 6;

    const float4 a = ((const float4*)(img + (size_t)row * DIM))[t];
    const float4 b = ((const float4*)(txt + (size_t)row * DIM))[t];

    float sa = a.x * a.x + a.y * a.y + a.z * a.z + a.w * a.w;
    float sb = b.x * b.x + b.y * b.y + b.z * b.z + b.w * b.w;
#pragma unroll
    for (int d = 1; d < 64; d <<= 1) {
        sa += __shfl_xor(sa, d, 64);
        sb += __shfl_xor(sb, d, 64);
    }
    __shared__ float red[3][4];
    if (lane == 0) { red[0][w] = sa; red[1][w] = sb; }
    __syncthreads();
    sa = red[0][0] + red[0][1] + red[0][2] + red[0][3];
    sb = red[1][0] + red[1][1] + red[1][2] + red[1][3];

    const float ia = 1.0f / fmaxf(sqrtf(sa), 1e-12f);
    const float ib = 1.0f / fmaxf(sqrtf(sb), 1e-12f);

    int ra = 0, rb = 0;
    ra = __builtin_amdgcn_cvt_pk_fp8_f32(a.x * ia, a.y * ia, ra, false);
    ra = __builtin_amdgcn_cvt_pk_fp8_f32(a.z * ia, a.w * ia, ra, true);
    rb = __builtin_amdgcn_cvt_pk_fp8_f32(b.x * ib, b.y * ib, rb, false);
    rb = __builtin_amdgcn_cvt_pk_fp8_f32(b.z * ib, b.w * ib, rb, true);
    ((int*)(img_f8 + (size_t)row * DIM))[t] = ra;
    ((int*)(txt_f8 + (size_t)row * DIM))[t] = rb;

    float dp = (a.x * b.x + a.y * b.y + a.z * b.z + a.w * b.w) * ia * ib;
#pragma unroll
    for (int d = 1; d < 64; d <<= 1) dp += __shfl_xor(dp, d, 64);
    if (lane == 0) red[2][w] = dp;
    __syncthreads();
    if (t == 0) {
        diag[row] = red[2][0] + red[2][1] + red[2][2] + red[2][3];
        S[row] = 0.0f;
    }
}

// ---------------------------------------------------------------------------
// Kernel 2: 256x128-tile MX-fp8 MFMA GEMM (C = A . B^T) with COUNTED VMCNT.
//   R0-R4 post-mortem: four different schedules all drained vmcnt(0) per
//   K-step and all landed at ~155us / 17.5% MfmaUtil.  T4 (m218: counted-vs-
//   drain0 = +38..73%) is the one lever never tested.  It requires prefetch
//   distance 2 => TRIPLE buffer (3 x 48 KiB = 144 KiB, 1 block/CU, 8 waves).
//   8 waves = 4M x 2N grid of 64x64 wave tiles; the fragment / MFMA / swizzle
//   code is the VERIFIED R3/R4 64x64 code, unchanged.
//   Per K-tile kt: { issue stage(kt+2 -> buf[kt+2 mod 3]) ; ds_read 16 b128
//   from buf[kt mod 3] ; 16 MFMA ; s_waitcnt vmcnt(6)  <- counted, NOT 0
//   (tile kt+1's 6 loads are older than the 6 just issued -> guaranteed
//   retired; kt+2's stay in flight) ; raw s_barrier }.
//   Raw s_barrier (not __syncthreads) — __syncthreads re-inserts the full
//   vmcnt(0) drain this round exists to remove.
//   Buffer-race check: stage(kt+2) overwrites buf holding tile kt-1, whose
//   reads finished before the end-of-(kt-1) barrier. Safe.
// ---------------------------------------------------------------------------
__global__ __launch_bounds__(512) void sim_lse_kernel(
    const uint8_t* __restrict__ A, const uint8_t* __restrict__ B,
    float* __restrict__ S)
{
    __shared__ __align__(16) uint8_t smem[3 * BUF_SZ];   // 144 KiB

    const int t     = threadIdx.x;       // 0..511
    const int lane  = t & 63;
    const int w     = t >> 6;            // wave 0..7
    const int waveM = w >> 1;            // 0..3 : 64 rows each (256 total)
    const int waveN = w & 1;             // 0..1 : 64 cols each (128 total)
    const int lr    = lane & 15;         // row-in-16-tile
    const int q     = lane >> 4;         // k-quarter (f8f6f4 frag layout)
    const int swz   = lr & 7;            // read-side XOR swizzle key

    const int rowA0 = blockIdx.y * BM;
    const int rowB0 = blockIdx.x * BN;
    const uint8_t* Ablk = A + (size_t)rowA0 * DIM;
    const uint8_t* Bblk = B + (size_t)rowB0 * DIM;

    const uint32_t lo_off = (uint32_t)(((2 * q) ^ swz) * 16);

    f32x4 acc[4][4] = {};

    // stage one K-tile (A 32K: 256 rows; B 16K: 128 rows) into buffer `base`.
    // 6 global_load_lds per thread (4 A + 2 B).  XOR chunk swizzle via
    // permuted GLOBAL source; LDS dest stays lane-linear (m104 constraint).
    auto stage = [&](int k0, uint32_t base) {
#pragma unroll
        for (int is = 0; is < 4; ++is) {             // A: 2048 chunks
            const int c   = is * 512 + t;            // 0..2047
            const int row = c >> 3;                  // 0..255
            const int col = (c & 7) ^ (row & 7);
            __builtin_amdgcn_global_load_lds(
                (const __attribute__((address_space(1))) void*)
                    (Ablk + (size_t)row * DIM + k0 + col * 16),
                (__attribute__((address_space(3))) void*)
                    &smem[base + (uint32_t)c * 16],
                16, 0, 0);
        }
#pragma unroll
        for (int is = 0; is < 2; ++is) {             // B: 1024 chunks
            const int c   = is * 512 + t;            // 0..1023
            const int row = c >> 3;                  // 0..127
            const int col = (c & 7) ^ (row & 7);
            __builtin_amdgcn_global_load_lds(
                (const __attribute__((address_space(1))) void*)
                    (Bblk + (size_t)row * DIM + k0 + col * 16),
                (__attribute__((address_space(3))) void*)
                    &smem[base + 32768u + (uint32_t)c * 16],
                16, 0, 0);
        }
    };

    // ---- prologue: tiles 0 and 1 in flight; wait only for tile 0 ----------
    stage(0,   0u);
    stage(BKF, BUF_SZ);
    asm volatile("s_waitcnt vmcnt(6)" ::: "memory");   // tile 0's 6 retired
    __builtin_amdgcn_s_barrier();

    uint32_t b0 = 0u, b1 = BUF_SZ, b2 = 2u * BUF_SZ;   // cur / next / next2

    // ---- main loop --------------------------------------------------------
#pragma unroll 1
    for (int kt = 0; kt < NT; ++kt) {
        if (kt < NT - 2) stage((kt + 2) * BKF, b2);    // issue, don't wait

        // Fragments (verified R3/R4 code): lane holds k = q*32..q*32+31 of
        // row (waveX*64 + i*16 + lr) = source chunks {2q,2q+1} at (c^swz).
        i32x8 af[4], bfr[4];
#pragma unroll
        for (int mi = 0; mi < 4; ++mi) {
            const uint8_t* base = &smem[b0 + (uint32_t)((waveM * 64 + mi * 16 + lr) * BKF)];
            i32x4 lo = *(const i32x4*)&base[lo_off];
            i32x4 hi = *(const i32x4*)&base[lo_off ^ 16u];
            af[mi] = (i32x8){lo.x, lo.y, lo.z, lo.w, hi.x, hi.y, hi.z, hi.w};
        }
#pragma unroll
        for (int ni = 0; ni < 4; ++ni) {
            const uint8_t* base = &smem[b0 + 32768u + (uint32_t)((waveN * 64 + ni * 16 + lr) * BKF)];
            i32x4 lo = *(const i32x4*)&base[lo_off];
            i32x4 hi = *(const i32x4*)&base[lo_off ^ 16u];
            bfr[ni] = (i32x8){lo.x, lo.y, lo.z, lo.w, hi.x, hi.y, hi.z, hi.w};
        }
#pragma unroll
        for (int mi = 0; mi < 4; ++mi)
#pragma unroll
            for (int ni = 0; ni < 4; ++ni)
                acc[mi][ni] = __builtin_amdgcn_mfma_scale_f32_16x16x128_f8f6f4(
                    af[mi], bfr[ni], acc[mi][ni],
                    0 /*fmtA=fp8*/, 0 /*fmtB=fp8*/,
                    0, 127 /*scaleA=1.0*/, 0, 127 /*scaleB=1.0*/);

        // counted wait: newest 6 (tile kt+2) may stay in flight; everything
        // older — i.e. tile kt+1's writes — is guaranteed retired.
        if (kt < NT - 2)      asm volatile("s_waitcnt vmcnt(6)" ::: "memory");
        else if (kt == NT - 2) asm volatile("s_waitcnt vmcnt(0)" ::: "memory");
        if (kt < NT - 1) __builtin_amdgcn_s_barrier();

        const uint32_t tmp = b0; b0 = b1; b1 = b2; b2 = tmp;   // rotate
    }

    // ---- epilogue: exp(s-1), DPP row-sum over 16 lanes, atomic into S -----
    // C/D layout (shape-determined): col = lane&15, row = (lane>>4)*4 + reg
    const float L2E = 1.44269504088896f;
    const int rowbase = rowA0 + waveM * 64;
#pragma unroll
    for (int mi = 0; mi < 4; ++mi) {
        float p0 = 0.f, p1 = 0.f, p2 = 0.f, p3 = 0.f;
#pragma unroll
        for (int ni = 0; ni < 4; ++ni) {
            p0 += exp2f(acc[mi][ni].x * L2E - L2E);
            p1 += exp2f(acc[mi][ni].y * L2E - L2E);
            p2 += exp2f(acc[mi][ni].z * L2E - L2E);
            p3 += exp2f(acc[mi][ni].w * L2E - L2E);
        }
        p0 = row_sum16(p0);   // VALU-only (DPP), zero LDS traffic
        p1 = row_sum16(p1);
        p2 = row_sum16(p2);
        p3 = row_sum16(p3);
        if ((lane & 15) == 0) {
            float* dst = &S[rowbase + mi * 16 + (lane >> 4) * 4];
            atomicAdd(dst + 0, p0);
            atomicAdd(dst + 1, p1);
            atomicAdd(dst + 2, p2);
            atomicAdd(dst + 3, p3);
        }
    }
}

// ---------------------------------------------------------------------------
// Kernel 3: out = mean(log(S_i) - diag_i)   UNCHANGED
// ---------------------------------------------------------------------------
__global__ __launch_bounds__(1024) void fin_kernel(
    const float* __restrict__ S, const float* __restrict__ diag,
    float* __restrict__ out)
{
    const int t = threadIdx.x;
    float s = 0.f;
    for (int i = t; i < N_ROWS; i += 1024) s += logf(S[i]) - diag[i];
#pragma unroll
    for (int d = 1; d < 64; d <<= 1) s += __shfl_xor(s, d, 64);
    __shared__ float red[16];
    if ((t & 63) == 0) red[t >> 6] = s;
    __syncthreads();
    if (t == 0) {
        float tot = 0.f;
#pragma unroll
        for (int i = 0; i < 16; ++i) tot += red[i];
        out[0] = tot * (1.0f / N_ROWS);
    }
}

// ---------------------------------------------------------------------------
extern "C" void kernel_launch(void* const* d_in, const int* in_sizes, int n_in,
                              void* d_out, int out_size, void* d_ws, size_t ws_size,
                              hipStream_t stream)
{
    const float* img = (const float*)d_in[0];
    const float* txt = (const float*)d_in[1];
    float* out = (float*)d_out;

    char* ws = (char*)d_ws;
    uint8_t* img_f8 = (uint8_t*)ws;                                  // 8 MiB
    uint8_t* txt_f8 = (uint8_t*)(ws + (size_t)N_ROWS * DIM);         // 8 MiB
    float*   S      = (float*)(ws + (size_t)N_ROWS * DIM * 2);       // 32 KiB
    float*   diag   = S + N_ROWS;                                    // 32 KiB

    nrm_kernel<<<N_ROWS, 256, 0, stream>>>(img, txt, img_f8, txt_f8, diag, S);
    dim3 grid(N_ROWS / BN, N_ROWS / BM);   // 64 x 32 = 2048 blocks
    sim_lse_kernel<<<grid, 512, 0, stream>>>(img_f8, txt_f8, S);
    fin_kernel<<<1, 1024, 0, stream>>>(S, diag, out);
}